// Round 11
// baseline (836.092 us; speedup 1.0000x reference)
//
#include <hip/hip_runtime.h>
#include <hip/hip_bf16.h>
#include <math.h>

#define NEG_SLOPE 0.2f

typedef short bf16x8 __attribute__((ext_vector_type(8)));
typedef float f32x4 __attribute__((ext_vector_type(4)));

__device__ __forceinline__ float wredsum(float v){
  #pragma unroll
  for (int o = 32; o; o >>= 1) v += __shfl_xor(v, o, 64);
  return v;
}
__device__ __forceinline__ float lrelu(float x){ return x >= 0.f ? x : NEG_SLOPE * x; }
__device__ __forceinline__ unsigned short f2bf(float f){
  __hip_bfloat16 h = __float2bfloat16(f);
  return *(unsigned short*)&h;
}
__device__ __forceinline__ float bf2f(unsigned short u){
  return __uint_as_float((unsigned)u << 16);
}

// async global->LDS, 16B per lane; lds dst = wave-uniform base + lane*16
__device__ __forceinline__ void gload_lds16(const unsigned short* g, unsigned short* l){
  __builtin_amdgcn_global_load_lds(
      (const __attribute__((address_space(1))) unsigned int*)g,
      (__attribute__((address_space(3))) unsigned int*)l, 16, 0, 0);
}

// ---- CSR construction ------------------------------------------------------
__global__ void k_deg(const int* __restrict__ ei, int* __restrict__ deg, int E){
  int e = blockIdx.x * 256 + threadIdx.x;
  if (e >= E) return;
  atomicAdd(&deg[ei[E + e]], 1);
}

// row width = deg[n] + 1 (self loop).  N = 16384 = 256 * 64, single block scan.
__global__ void k_scan(const int* __restrict__ deg, int* __restrict__ row_start, int N){
  __shared__ int s[256];
  int t = threadIdx.x;
  int base = t * 64;
  int sum = 0;
  for (int i = 0; i < 64; ++i) sum += deg[base + i] + 1;
  s[t] = sum;
  __syncthreads();
  for (int off = 1; off < 256; off <<= 1){
    int v = (t >= off) ? s[t - off] : 0;
    __syncthreads();
    s[t] += v;
    __syncthreads();
  }
  int run = s[t] - sum;   // exclusive
  for (int i = 0; i < 64; ++i){ row_start[base + i] = run; run += deg[base + i] + 1; }
  if (t == 255) row_start[N] = run;
}

// self slots (idx < N) + edge slots (idx >= N) in one launch
__global__ void k_csr_build(const int* __restrict__ ei, const int* __restrict__ row_start,
                            int* __restrict__ fill, int* __restrict__ csr_src,
                            int* __restrict__ csr_eid, int N, int E){
  int idx = blockIdx.x * 256 + threadIdx.x;
  if (idx < N){
    int p = row_start[idx];
    csr_src[p] = idx;        // self loop in slot 0
    csr_eid[p] = E;          // sentinel
  } else {
    int e = idx - N;
    if (e >= E) return;
    int dst = ei[E + e];
    int p = row_start[dst] + 1 + atomicAdd(&fill[dst], 1);
    csr_src[p] = ei[e];
    csr_eid[p] = e;
  }
}

// merged: self-loop mean attr (first N*32 threads) + permuted bf16 copy (rest)
__global__ void k_eaprep(const float* __restrict__ ea, const int* __restrict__ csr_eid,
                         const int* __restrict__ row_start,
                         unsigned short* __restrict__ ea_perm, int N, int Eaug, int E){
  int idx = blockIdx.x * 256 + threadIdx.x;
  if (idx < N * 32){
    int n = idx >> 5, k = idx & 31;
    int rs = row_start[n], re = row_start[n + 1];
    float sum = 0.f;
    for (int i = rs + 1; i < re; ++i)
      sum += ea[(size_t)csr_eid[i] * 32 + k];
    float d = (float)max(re - rs - 1, 1);
    ea_perm[(size_t)rs * 32 + k] = f2bf(sum / d);
  } else {
    int j = idx - N * 32;
    int p = j >> 3, q = j & 7;
    if (p >= Eaug) return;
    int e = csr_eid[p];
    if (e >= E) return;   // self slot handled above
    float4 v = ((const float4*)(ea + (size_t)e * 32))[q];
    ushort4 o;
    o.x = f2bf(v.x); o.y = f2bf(v.y); o.z = f2bf(v.z); o.w = f2bf(v.w);
    *(ushort4*)&ea_perm[(size_t)p * 32 + q * 4] = o;
  }
}

// ---- dtype prep ------------------------------------------------------------
__global__ void k_cvt_bf16(const float* __restrict__ in, unsigned short* __restrict__ out, int n4){
  int idx = blockIdx.x * 256 + threadIdx.x;
  if (idx >= n4) return;
  float4 v = *(const float4*)&in[idx * 4];
  ushort4 o;
  o.x = f2bf(v.x); o.y = f2bf(v.y); o.z = f2bf(v.z); o.w = f2bf(v.w);
  *(ushort4*)&out[idx * 4] = o;
}

// ---- weight prep ------------------------------------------------------------
// W[K,N] fp32 -> Wt[N,K] bf16; blockIdx.z selects (W0->Wt0, W1->Wt1).
__global__ __launch_bounds__(256) void k_transpose2_bf16(const float* __restrict__ W0,
    const float* __restrict__ W1, unsigned short* __restrict__ Wt0,
    unsigned short* __restrict__ Wt1, int K, int N){
  __shared__ float tile[64][65];
  const float* W = blockIdx.z ? W1 : W0;
  unsigned short* Wt = blockIdx.z ? Wt1 : Wt0;
  int n0 = blockIdx.x * 64, k0 = blockIdx.y * 64;
  int col = threadIdx.x & 63, rq = threadIdx.x >> 6;
  #pragma unroll
  for (int i = 0; i < 16; ++i){
    int r = rq * 16 + i;
    tile[r][col] = W[(size_t)(k0 + r) * N + n0 + col];
  }
  __syncthreads();
  #pragma unroll
  for (int i = 0; i < 16; ++i){
    int r = rq * 16 + i;
    Wt[(size_t)(n0 + r) * K + k0 + col] = f2bf(tile[col][r]);
  }
}

__global__ void k_transpose_we(const float* __restrict__ We, unsigned short* __restrict__ WeT, int FO){
  int idx = blockIdx.x * 256 + threadIdx.x;
  if (idx >= 32 * FO) return;
  int k = idx / FO, n = idx % FO;
  WeT[n * 32 + k] = f2bf(We[idx]);
}

// ---- bf16 MFMA GEMM, dual-output (z: 0->L, 1->R), BK=32, global_load_lds ---
// (r10 structure: XCD M-tile swizzle + DMA staging + LDS-repacked epilogue)
__global__ void k_mfma_gemm2(const unsigned short* __restrict__ A,
    const unsigned short* __restrict__ BtL, const unsigned short* __restrict__ BtR,
    const float* __restrict__ biasL, const float* __restrict__ biasR,
    unsigned short* __restrict__ CL, unsigned short* __restrict__ CR, int FO, int K){
  __shared__ unsigned short lds[16384];     // 32 KB: As[4096] + Bs[4096] / C-tile[16384]
  unsigned short* As = lds;                 // [128][32]
  unsigned short* Bs = lds + 4096;          // [128][32]
  const unsigned short* Bt = blockIdx.z ? BtR : BtL;
  const float* bias = blockIdx.z ? biasR : biasL;
  unsigned short* C = blockIdx.z ? CR : CL;
  int t = threadIdx.x;
  int mb = blockIdx.x, nb = blockIdx.y;
  int lane = t & 63, w = t >> 6;
  int wm = (w & 1) * 64, wn = (w >> 1) * 64;
  int lo = lane & 15, hi = lane >> 4;
  int srow = w * 32 + (lane >> 2);
  int scol = (lane & 3) * 8;                 // shorts
  const unsigned short* Ap0 = A + (size_t)(mb * 128 + srow) * K + scol;
  const unsigned short* Ap1 = Ap0 + (size_t)16 * K;
  const unsigned short* Bp0 = Bt + (size_t)(nb * 128 + srow) * K + scol;
  const unsigned short* Bp1 = Bp0 + (size_t)16 * K;
  unsigned short* Asd0 = As + (w * 32) * 32;
  unsigned short* Asd1 = As + (w * 32 + 16) * 32;
  unsigned short* Bsd0 = Bs + (w * 32) * 32;
  unsigned short* Bsd1 = Bs + (w * 32 + 16) * 32;
  f32x4 acc[4][4] = {};
  for (int k0 = 0; k0 < K; k0 += 32){
    gload_lds16(Ap0 + k0, Asd0);
    gload_lds16(Ap1 + k0, Asd1);
    gload_lds16(Bp0 + k0, Bsd0);
    gload_lds16(Bp1 + k0, Bsd1);
    __syncthreads();
    bf16x8 af[4], bfr[4];
    #pragma unroll
    for (int i = 0; i < 4; ++i){
      af[i]  = *(const bf16x8*)&As[(wm + i * 16 + lo) * 32 + hi * 8];
      bfr[i] = *(const bf16x8*)&Bs[(wn + i * 16 + lo) * 32 + hi * 8];
    }
    #pragma unroll
    for (int mi = 0; mi < 4; ++mi)
      #pragma unroll
      for (int ni = 0; ni < 4; ++ni)
        acc[mi][ni] = __builtin_amdgcn_mfma_f32_16x16x32_bf16(af[mi], bfr[ni], acc[mi][ni], 0, 0, 0);
    __syncthreads();
  }
  #pragma unroll
  for (int ni = 0; ni < 4; ++ni){
    int col = wn + ni * 16 + lo;
    float bv = bias[nb * 128 + col];
    #pragma unroll
    for (int mi = 0; mi < 4; ++mi){
      int row = wm + mi * 16 + hi * 4;
      #pragma unroll
      for (int r = 0; r < 4; ++r)
        lds[(row + r) * 128 + col] = f2bf(acc[mi][ni][r] + bv);
    }
  }
  __syncthreads();
  #pragma unroll
  for (int q = 0; q < 8; ++q){
    int idx = q * 256 + t;
    int row = idx >> 4;
    int cs = (idx & 15) * 8;
    *(float4*)&C[(size_t)(mb * 128 + row) * FO + nb * 128 + cs] = *(float4*)&lds[row * 128 + cs];
  }
}

// ---- fused EW-MFMA + logit + online-softmax + aggregation ------------------
// One block per dst node. Per 16-edge group: waves compute their FO/4-col slice
// of EW = ea@We via MFMA into LDS; phase A gathers xl (stashed packed in regs)
// and wave-reduces partial logits; phase B sums partials, online-softmax, acc.
template<int DPT, typename OutT>   // FO = 256*DPT
__global__ __launch_bounds__(256) void k_agg2(const unsigned short* __restrict__ XL,
    const unsigned short* __restrict__ XRb, const unsigned short* __restrict__ ea_perm,
    const unsigned short* __restrict__ WeT, const int* __restrict__ csr_src,
    const int* __restrict__ row_start, const float* __restrict__ att,
    const float* __restrict__ bc, OutT* __restrict__ out){
  const int FO = 256 * DPT;
  const int STR = FO + 8;                 // rows 16B-aligned; 4-row bank offset = 16 (2-way, free)
  __shared__ unsigned short ewb[16 * (256 * DPT + 8)];
  __shared__ float tpart[16][4];
  int t = threadIdx.x;
  int lane = t & 63, w = t >> 6;
  int lo = lane & 15, hi = lane >> 4;
  int n = blockIdx.x;
  int rs = row_start[n], re = row_start[n + 1];
  int d0 = t * DPT;
  float xr[DPT], at[DPT], acc[DPT];
  if (DPT == 4){
    ushort4 u = *(const ushort4*)&XRb[(size_t)n * FO + d0];
    xr[0]=bf2f(u.x); xr[1]=bf2f(u.y); xr[2]=bf2f(u.z); xr[3]=bf2f(u.w);
  } else if (DPT == 2){
    ushort2 u = *(const ushort2*)&XRb[(size_t)n * FO + d0];
    xr[0]=bf2f(u.x); xr[1]=bf2f(u.y);
  } else {
    xr[0] = bf2f(XRb[(size_t)n * FO + d0]);
  }
  #pragma unroll
  for (int d = 0; d < DPT; ++d){ at[d] = att[d0 + d]; acc[d] = 0.f; }
  float m = -1e30f, den = 0.f;
  int wcol0 = w * (FO / 4);
  unsigned int xlp[16 * ((DPT + 1) / 2)];   // packed bf16 stash (phase A -> B)
  for (int g = rs; g < re; g += 16){
    int ne = min(16, re - g);
    // ---- MFMA: EW rows for edges [g, g+16) (layouts mirror verified k_mfma_ew)
    {
      int e = min(g + lo, re - 1);
      bf16x8 af = *(const bf16x8*)&ea_perm[(size_t)e * 32 + hi * 8];
      #pragma unroll
      for (int ct = 0; ct < FO / 64; ++ct){
        int col = wcol0 + ct * 16 + lo;
        bf16x8 bfr = *(const bf16x8*)&WeT[(size_t)col * 32 + hi * 8];
        f32x4 z = {0.f, 0.f, 0.f, 0.f};
        f32x4 a = __builtin_amdgcn_mfma_f32_16x16x32_bf16(af, bfr, z, 0, 0, 0);
        #pragma unroll
        for (int r = 0; r < 4; ++r)
          ewb[(hi * 4 + r) * STR + col] = f2bf(a[r]);
      }
    }
    __syncthreads();
    // ---- phase A: partial logits (thread owns DPT dims; xl stashed packed)
    for (int k = 0; k < ne; ++k){
      int s = csr_src[g + k];
      const unsigned short* xp = &XL[(size_t)s * FO + d0];
      const unsigned short* ep = &ewb[k * STR + d0];
      float xl[DPT], ew[DPT];
      if (DPT == 4){
        uint2 q = *(const uint2*)xp;
        xlp[k * 2] = q.x; xlp[k * 2 + 1] = q.y;
        xl[0]=__uint_as_float(q.x << 16); xl[1]=__uint_as_float(q.x & 0xffff0000u);
        xl[2]=__uint_as_float(q.y << 16); xl[3]=__uint_as_float(q.y & 0xffff0000u);
        ushort4 ue = *(const ushort4*)ep;
        ew[0]=bf2f(ue.x); ew[1]=bf2f(ue.y); ew[2]=bf2f(ue.z); ew[3]=bf2f(ue.w);
      } else if (DPT == 2){
        unsigned int q = *(const unsigned int*)xp;
        xlp[k] = q;
        xl[0]=__uint_as_float(q << 16); xl[1]=__uint_as_float(q & 0xffff0000u);
        ushort2 ue = *(const ushort2*)ep;
        ew[0]=bf2f(ue.x); ew[1]=bf2f(ue.y);
      } else {
        unsigned short q = *xp;
        xlp[k] = q;
        xl[0] = bf2f(q);
        ew[0] = bf2f(*ep);
      }
      float p = 0.f;
      #pragma unroll
      for (int d = 0; d < DPT; ++d) p += at[d] * lrelu(xl[d] + xr[d] + ew[d]);
      p = wredsum(p);
      if (lane == 0) tpart[k][w] = p;
    }
    __syncthreads();
    // ---- phase B: full logits, online softmax, payload from stashed xl
    for (int k = 0; k < ne; ++k){
      float tt = tpart[k][0] + tpart[k][1] + tpart[k][2] + tpart[k][3];
      float mn = fmaxf(m, tt);
      float sc = __expf(m - mn);     // first iter: exp(-huge) = 0
      float f = __expf(tt - mn);
      den = den * sc + f;
      float xl[DPT];
      if (DPT == 4){
        unsigned int qx = xlp[k * 2], qy = xlp[k * 2 + 1];
        xl[0]=__uint_as_float(qx << 16); xl[1]=__uint_as_float(qx & 0xffff0000u);
        xl[2]=__uint_as_float(qy << 16); xl[3]=__uint_as_float(qy & 0xffff0000u);
      } else if (DPT == 2){
        unsigned int q = xlp[k];
        xl[0]=__uint_as_float(q << 16); xl[1]=__uint_as_float(q & 0xffff0000u);
      } else {
        xl[0] = bf2f((unsigned short)xlp[k]);
      }
      #pragma unroll
      for (int d = 0; d < DPT; ++d) acc[d] = acc[d] * sc + f * xl[d];
      m = mn;
    }
    __syncthreads();   // before next group's ewb overwrite
  }
  float inv = 1.f / den;
  float o[DPT];
  #pragma unroll
  for (int d = 0; d < DPT; ++d) o[d] = fmaxf(acc[d] * inv + bc[d0 + d], 0.f);
  if (sizeof(OutT) == 2){
    unsigned short* op = (unsigned short*)out + (size_t)n * FO + d0;
    if (DPT == 4){ ushort4 u; u.x=f2bf(o[0]); u.y=f2bf(o[1]); u.z=f2bf(o[2]); u.w=f2bf(o[3]); *(ushort4*)op = u; }
    else if (DPT == 2){ ushort2 u; u.x=f2bf(o[0]); u.y=f2bf(o[1]); *(ushort2*)op = u; }
    else op[0] = f2bf(o[0]);
  } else {
    float* op = (float*)out + (size_t)n * FO + d0;
    #pragma unroll
    for (int d = 0; d < DPT; ++d) op[d] = o[d];
  }
}

// ---- fused pool + fc1 (one block per graph; batch is sorted) ----------------
__global__ void k_poolfc(const float* __restrict__ H, const int* __restrict__ batch,
                         const float* __restrict__ w, const float* __restrict__ b,
                         float* __restrict__ z, int N){
  __shared__ float ps[256];
  __shared__ int se[2];
  int g = blockIdx.x;
  int t = threadIdx.x;
  if (t < 2){
    int target = g + t;
    int lo = 0, hi = N;
    while (lo < hi){ int mid = (lo + hi) >> 1; if (batch[mid] < target) lo = mid + 1; else hi = mid; }
    se[t] = lo;
  }
  __syncthreads();
  int s = se[0], e = se[1];
  float a = 0.f;
  for (int n = s; n < e; ++n) a += H[(size_t)n * 256 + t];
  ps[t] = a;
  __syncthreads();
  if (t < 64){
    float acc = 0.f;
    for (int k = 0; k < 256; ++k) acc += ps[k] * w[k * 64 + t];
    z[g * 64 + t] = acc / fmaxf((float)(e - s), 1.f) + b[t];
  }
}

__global__ void k_head(const float* __restrict__ z, const float* __restrict__ bn_g,
                       const float* __restrict__ bn_b, const float* __restrict__ w2,
                       const float* __restrict__ b2, float* __restrict__ out){
  __shared__ float mu_s[64], is_s[64];
  int t = threadIdx.x;  // 128 threads
  if (t < 64){
    float mu = 0.f, m2 = 0.f;
    for (int g = 0; g < 128; ++g){ float v = z[g * 64 + t]; mu += v; m2 += v * v; }
    mu /= 128.f; m2 /= 128.f;
    float var = m2 - mu * mu;
    mu_s[t] = mu;
    is_s[t] = rsqrtf(var + 1e-5f);
  }
  __syncthreads();
  float o = b2[0];
  for (int j = 0; j < 64; ++j){
    float v = (z[t * 64 + j] - mu_s[j]) * is_s[j] * bn_g[j] + bn_b[j];
    o += fmaxf(v, 0.f) * w2[j];
  }
  out[t] = o;
}

extern "C" void kernel_launch(void* const* d_in, const int* in_sizes, int n_in,
                              void* d_out, int out_size, void* d_ws, size_t ws_size,
                              hipStream_t stream){
  const int N = 16384, E = 131072, Eaug = E + N, NG = 128;
  const float* x     = (const float*)d_in[0];
  const int*   ei    = (const int*)  d_in[1];
  const float* ea    = (const float*)d_in[2];
  const int*   batch = (const int*)  d_in[3];
  const float* Wl[3]  = {(const float*)d_in[4],  (const float*)d_in[11], (const float*)d_in[18]};
  const float* bl[3]  = {(const float*)d_in[5],  (const float*)d_in[12], (const float*)d_in[19]};
  const float* Wr[3]  = {(const float*)d_in[6],  (const float*)d_in[13], (const float*)d_in[20]};
  const float* br[3]  = {(const float*)d_in[7],  (const float*)d_in[14], (const float*)d_in[21]};
  const float* We[3]  = {(const float*)d_in[8],  (const float*)d_in[15], (const float*)d_in[22]};
  const float* att[3] = {(const float*)d_in[9],  (const float*)d_in[16], (const float*)d_in[23]};
  const float* bc[3]  = {(const float*)d_in[10], (const float*)d_in[17], (const float*)d_in[24]};
  const float* fc1_w = (const float*)d_in[25];
  const float* fc1_b = (const float*)d_in[26];
  const float* bn_g  = (const float*)d_in[27];
  const float* bn_b  = (const float*)d_in[28];
  const float* fc2_w = (const float*)d_in[29];
  const float* fc2_b = (const float*)d_in[30];
  float* out = (float*)d_out;

  char* wsb = (char*)d_ws;
  size_t off = 0;
  auto alloc = [&](size_t bytes) -> char* {
    char* p = wsb + off;
    off = (off + bytes + 255) & ~(size_t)255;
    return p;
  };
  int*   deg       = (int*)  alloc((size_t)N * 4);
  int*   fill      = (int*)  alloc((size_t)N * 4);
  int*   row_start = (int*)  alloc((size_t)(N + 1) * 4);
  int*   csr_src   = (int*)  alloc((size_t)Eaug * 4);
  int*   csr_eid   = (int*)  alloc((size_t)Eaug * 4);
  unsigned short* ea_perm = (unsigned short*)alloc((size_t)Eaug * 32 * 2);
  unsigned short* XL   = (unsigned short*)alloc((size_t)N * 1024 * 2); // 32 MB
  unsigned short* XRb  = (unsigned short*)alloc((size_t)N * 1024 * 2); // 32 MB
  unsigned short* bufA = (unsigned short*)alloc((size_t)N * 1024 * 2); // 32 MB: Xb / L2-out
  unsigned short* bufB = (unsigned short*)alloc((size_t)N * 512 * 4);  // 32 MB: L1-out bf16 / L3-out fp32
  unsigned short* WtL  = (unsigned short*)alloc((size_t)1024 * 1024 * 2);
  unsigned short* WtR  = (unsigned short*)alloc((size_t)1024 * 1024 * 2);
  unsigned short* WeT  = (unsigned short*)alloc((size_t)1024 * 32 * 2);
  float* zbuf      = (float*)alloc((size_t)NG * 64 * 4);
  // (EW ring eliminated — EW now computed in-kernel via MFMA into LDS)

  hipMemsetAsync(deg, 0, (size_t)2 * N * 4, stream);  // deg + fill (adjacent)

  k_deg<<<E / 256, 256, 0, stream>>>(ei, deg, E);
  k_scan<<<1, 256, 0, stream>>>(deg, row_start, N);
  k_csr_build<<<(N + E) / 256, 256, 0, stream>>>(ei, row_start, fill, csr_src, csr_eid, N, E);
  k_eaprep<<<(N * 32 + Eaug * 8 + 255) / 256, 256, 0, stream>>>(ea, csr_eid, row_start, ea_perm, N, Eaug, E);
  k_cvt_bf16<<<(N * 256 / 4) / 256, 256, 0, stream>>>(x, bufA, N * 256 / 4);  // Xb in bufA

  const int fin[3] = {256, 512, 1024};
  const int fo[3]  = {512, 1024, 256};
  const unsigned short* Ain[3] = {bufA, bufB, bufA};

  for (int L = 0; L < 3; ++L){
    int FI = fin[L], FO = fo[L];
    k_transpose2_bf16<<<dim3(FO / 64, FI / 64, 2), 256, 0, stream>>>(Wl[L], Wr[L], WtL, WtR, FI, FO);
    k_transpose_we<<<(32 * FO + 255) / 256, 256, 0, stream>>>(We[L], WeT, FO);
    dim3 gg(N / 128, FO / 128, 2);   // M-tile = blockIdx.x: XCD locality for A
    k_mfma_gemm2<<<gg, 256, 0, stream>>>(Ain[L], WtL, WtR, bl[L], br[L], XL, XRb, FO, FI);
    if (FO == 512)
      k_agg2<2, unsigned short><<<N, 256, 0, stream>>>(XL, XRb, ea_perm, WeT, csr_src, row_start, att[L], bc[L], bufB);
    else if (FO == 1024)
      k_agg2<4, unsigned short><<<N, 256, 0, stream>>>(XL, XRb, ea_perm, WeT, csr_src, row_start, att[L], bc[L], bufA);
    else
      k_agg2<1, float><<<N, 256, 0, stream>>>(XL, XRb, ea_perm, WeT, csr_src, row_start, att[L], bc[L], (float*)bufB);
  }

  k_poolfc<<<NG, 256, 0, stream>>>((const float*)bufB, batch, fc1_w, fc1_b, zbuf, N);
  k_head<<<1, 128, 0, stream>>>(zbuf, bn_g, bn_b, fc2_w, fc2_b, out);
}

// Round 12
// 670.476 us; speedup vs baseline: 1.2470x; 1.2470x over previous
//
#include <hip/hip_runtime.h>
#include <hip/hip_bf16.h>
#include <math.h>

#define NEG_SLOPE 0.2f

typedef short bf16x8 __attribute__((ext_vector_type(8)));
typedef float f32x4 __attribute__((ext_vector_type(4)));

__device__ __forceinline__ float wredsum(float v){
  #pragma unroll
  for (int o = 32; o; o >>= 1) v += __shfl_xor(v, o, 64);
  return v;
}
__device__ __forceinline__ float lrelu(float x){ return x >= 0.f ? x : NEG_SLOPE * x; }
__device__ __forceinline__ unsigned short f2bf(float f){
  __hip_bfloat16 h = __float2bfloat16(f);
  return *(unsigned short*)&h;
}
__device__ __forceinline__ float bf2f(unsigned short u){
  return __uint_as_float((unsigned)u << 16);
}

// async global->LDS, 16B per lane; lds dst = wave-uniform base + lane*16
__device__ __forceinline__ void gload_lds16(const unsigned short* g, unsigned short* l){
  __builtin_amdgcn_global_load_lds(
      (const __attribute__((address_space(1))) unsigned int*)g,
      (__attribute__((address_space(3))) unsigned int*)l, 16, 0, 0);
}

// ---- CSR construction ------------------------------------------------------
__global__ void k_deg(const int* __restrict__ ei, int* __restrict__ deg, int E){
  int e = blockIdx.x * 256 + threadIdx.x;
  if (e >= E) return;
  atomicAdd(&deg[ei[E + e]], 1);
}

// row width = deg[n] + 1 (self loop).  N = 16384 = 256 * 64, single block scan.
__global__ void k_scan(const int* __restrict__ deg, int* __restrict__ row_start, int N){
  __shared__ int s[256];
  int t = threadIdx.x;
  int base = t * 64;
  int sum = 0;
  for (int i = 0; i < 64; ++i) sum += deg[base + i] + 1;
  s[t] = sum;
  __syncthreads();
  for (int off = 1; off < 256; off <<= 1){
    int v = (t >= off) ? s[t - off] : 0;
    __syncthreads();
    s[t] += v;
    __syncthreads();
  }
  int run = s[t] - sum;   // exclusive
  for (int i = 0; i < 64; ++i){ row_start[base + i] = run; run += deg[base + i] + 1; }
  if (t == 255) row_start[N] = run;
}

// self slots (idx < N) + edge slots (idx >= N) in one launch
__global__ void k_csr_build(const int* __restrict__ ei, const int* __restrict__ row_start,
                            int* __restrict__ fill, int* __restrict__ csr_src,
                            int* __restrict__ csr_eid, int N, int E){
  int idx = blockIdx.x * 256 + threadIdx.x;
  if (idx < N){
    int p = row_start[idx];
    csr_src[p] = idx;        // self loop in slot 0
    csr_eid[p] = E;          // sentinel
  } else {
    int e = idx - N;
    if (e >= E) return;
    int dst = ei[E + e];
    int p = row_start[dst] + 1 + atomicAdd(&fill[dst], 1);
    csr_src[p] = ei[e];
    csr_eid[p] = e;
  }
}

// merged: self-loop mean attr (first N*32 threads) + permuted bf16 copy (rest)
__global__ void k_eaprep(const float* __restrict__ ea, const int* __restrict__ csr_eid,
                         const int* __restrict__ row_start,
                         unsigned short* __restrict__ ea_perm, int N, int Eaug, int E){
  int idx = blockIdx.x * 256 + threadIdx.x;
  if (idx < N * 32){
    int n = idx >> 5, k = idx & 31;
    int rs = row_start[n], re = row_start[n + 1];
    float sum = 0.f;
    for (int i = rs + 1; i < re; ++i)
      sum += ea[(size_t)csr_eid[i] * 32 + k];
    float d = (float)max(re - rs - 1, 1);
    ea_perm[(size_t)rs * 32 + k] = f2bf(sum / d);
  } else {
    int j = idx - N * 32;
    int p = j >> 3, q = j & 7;
    if (p >= Eaug) return;
    int e = csr_eid[p];
    if (e >= E) return;   // self slot handled above
    float4 v = ((const float4*)(ea + (size_t)e * 32))[q];
    ushort4 o;
    o.x = f2bf(v.x); o.y = f2bf(v.y); o.z = f2bf(v.z); o.w = f2bf(v.w);
    *(ushort4*)&ea_perm[(size_t)p * 32 + q * 4] = o;
  }
}

// ---- dtype prep ------------------------------------------------------------
__global__ void k_cvt_bf16(const float* __restrict__ in, unsigned short* __restrict__ out, int n4){
  int idx = blockIdx.x * 256 + threadIdx.x;
  if (idx >= n4) return;
  float4 v = *(const float4*)&in[idx * 4];
  ushort4 o;
  o.x = f2bf(v.x); o.y = f2bf(v.y); o.z = f2bf(v.z); o.w = f2bf(v.w);
  *(ushort4*)&out[idx * 4] = o;
}

// ---- weight prep ------------------------------------------------------------
// W[K,N] fp32 -> Wt[N,K] bf16; blockIdx.z selects (W0->Wt0, W1->Wt1).
__global__ __launch_bounds__(256) void k_transpose2_bf16(const float* __restrict__ W0,
    const float* __restrict__ W1, unsigned short* __restrict__ Wt0,
    unsigned short* __restrict__ Wt1, int K, int N){
  __shared__ float tile[64][65];
  const float* W = blockIdx.z ? W1 : W0;
  unsigned short* Wt = blockIdx.z ? Wt1 : Wt0;
  int n0 = blockIdx.x * 64, k0 = blockIdx.y * 64;
  int col = threadIdx.x & 63, rq = threadIdx.x >> 6;
  #pragma unroll
  for (int i = 0; i < 16; ++i){
    int r = rq * 16 + i;
    tile[r][col] = W[(size_t)(k0 + r) * N + n0 + col];
  }
  __syncthreads();
  #pragma unroll
  for (int i = 0; i < 16; ++i){
    int r = rq * 16 + i;
    Wt[(size_t)(n0 + r) * K + k0 + col] = f2bf(tile[col][r]);
  }
}

__global__ void k_transpose_we(const float* __restrict__ We, unsigned short* __restrict__ WeT, int FO){
  int idx = blockIdx.x * 256 + threadIdx.x;
  if (idx >= 32 * FO) return;
  int k = idx / FO, n = idx % FO;
  WeT[n * 32 + k] = f2bf(We[idx]);
}

// ---- bf16 MFMA GEMM, dual-output (z: 0->L, 1->R), BK=64 split-half ---------
// C[M,FO] = A[M,K] @ Bt[FO,K]^T + bias, output bf16.  A bf16, K % 64 == 0.
// blockIdx.x = M-tile (%8 grid): XCD-locality for A (r9: FETCH 133->31 MB).
// r10 structure + BK=64: two [128][32] tiles per operand (keeps 64B rows =
// 2-way-free LDS banking AND contiguous global_load_lds order); halves the
// barrier count per K (m97's ~20% barrier-drain stall).
__global__ void k_mfma_gemm2(const unsigned short* __restrict__ A,
    const unsigned short* __restrict__ BtL, const unsigned short* __restrict__ BtR,
    const float* __restrict__ biasL, const float* __restrict__ biasR,
    unsigned short* __restrict__ CL, unsigned short* __restrict__ CR, int FO, int K){
  __shared__ unsigned short lds[16384];     // 32 KB: As0|As1|Bs0|Bs1 / C-tile
  unsigned short* As0 = lds;                // [128][32], K-half 0
  unsigned short* As1 = lds + 4096;         // [128][32], K-half 1
  unsigned short* Bs0 = lds + 8192;
  unsigned short* Bs1 = lds + 12288;
  const unsigned short* Bt = blockIdx.z ? BtR : BtL;
  const float* bias = blockIdx.z ? biasR : biasL;
  unsigned short* C = blockIdx.z ? CR : CL;
  int t = threadIdx.x;
  int mb = blockIdx.x, nb = blockIdx.y;
  int lane = t & 63, w = t >> 6;
  int wm = (w & 1) * 64, wn = (w >> 1) * 64;
  int lo = lane & 15, hi = lane >> 4;
  int srow = w * 32 + (lane >> 2);
  int scol = (lane & 3) * 8;                 // shorts
  const unsigned short* Ap0 = A + (size_t)(mb * 128 + srow) * K + scol;
  const unsigned short* Ap1 = Ap0 + (size_t)16 * K;
  const unsigned short* Bp0 = Bt + (size_t)(nb * 128 + srow) * K + scol;
  const unsigned short* Bp1 = Bp0 + (size_t)16 * K;
  unsigned short* Ad00 = As0 + (w * 32) * 32;       // wave-uniform LDS bases
  unsigned short* Ad01 = As0 + (w * 32 + 16) * 32;
  unsigned short* Ad10 = As1 + (w * 32) * 32;
  unsigned short* Ad11 = As1 + (w * 32 + 16) * 32;
  unsigned short* Bd00 = Bs0 + (w * 32) * 32;
  unsigned short* Bd01 = Bs0 + (w * 32 + 16) * 32;
  unsigned short* Bd10 = Bs1 + (w * 32) * 32;
  unsigned short* Bd11 = Bs1 + (w * 32 + 16) * 32;
  f32x4 acc[4][4] = {};
  for (int k0 = 0; k0 < K; k0 += 64){
    gload_lds16(Ap0 + k0, Ad00);
    gload_lds16(Ap1 + k0, Ad01);
    gload_lds16(Ap0 + k0 + 32, Ad10);
    gload_lds16(Ap1 + k0 + 32, Ad11);
    gload_lds16(Bp0 + k0, Bd00);
    gload_lds16(Bp1 + k0, Bd01);
    gload_lds16(Bp0 + k0 + 32, Bd10);
    gload_lds16(Bp1 + k0 + 32, Bd11);
    __syncthreads();
    #pragma unroll
    for (int ks = 0; ks < 2; ++ks){
      const unsigned short* Asx = ks ? As1 : As0;
      const unsigned short* Bsx = ks ? Bs1 : Bs0;
      bf16x8 af[4], bfr[4];
      #pragma unroll
      for (int i = 0; i < 4; ++i){
        af[i]  = *(const bf16x8*)&Asx[(wm + i * 16 + lo) * 32 + hi * 8];
        bfr[i] = *(const bf16x8*)&Bsx[(wn + i * 16 + lo) * 32 + hi * 8];
      }
      #pragma unroll
      for (int mi = 0; mi < 4; ++mi)
        #pragma unroll
        for (int ni = 0; ni < 4; ++ni)
          acc[mi][ni] = __builtin_amdgcn_mfma_f32_16x16x32_bf16(af[mi], bfr[ni], acc[mi][ni], 0, 0, 0);
    }
    __syncthreads();
  }
  // epilogue: acc -> LDS C-tile [128][128] shorts -> coalesced dwordx4 stores
  #pragma unroll
  for (int ni = 0; ni < 4; ++ni){
    int col = wn + ni * 16 + lo;
    float bv = bias[nb * 128 + col];
    #pragma unroll
    for (int mi = 0; mi < 4; ++mi){
      int row = wm + mi * 16 + hi * 4;
      #pragma unroll
      for (int r = 0; r < 4; ++r)
        lds[(row + r) * 128 + col] = f2bf(acc[mi][ni][r] + bv);
    }
  }
  __syncthreads();
  #pragma unroll
  for (int q = 0; q < 8; ++q){
    int idx = q * 256 + t;
    int row = idx >> 4;
    int cs = (idx & 15) * 8;
    *(float4*)&C[(size_t)(mb * 128 + row) * FO + nb * 128 + cs] = *(float4*)&lds[row * 128 + cs];
  }
}

// ---- EW MFMA GEMM (K=32, no LDS): EW[e-rs0,:] = ea_perm[e,:] @ WeT[n,:]^T --
// blockIdx.x = edge-tile (grid %8): XCD locality for ea rows.
__global__ void k_mfma_ew(const unsigned short* __restrict__ Ap,
    const unsigned short* __restrict__ WeT, unsigned short* __restrict__ EW,
    const int* __restrict__ row_start, int c0, int c1, int N){
  int rs0 = row_start[c0], rs1 = row_start[c1];
  int e_base = rs0 + blockIdx.x * 128;
  if (e_base >= rs1) return;
  int t = threadIdx.x;
  int nb = blockIdx.y;
  int lane = t & 63, w = t >> 6;
  int wm = (w & 1) * 64, wn = (w >> 1) * 64;
  int lo = lane & 15, hi = lane >> 4;
  bf16x8 af[4], bf4[4];
  #pragma unroll
  for (int i = 0; i < 4; ++i){
    int e = min(e_base + wm + i * 16 + lo, rs1 - 1);
    af[i] = *(const bf16x8*)&Ap[(size_t)e * 32 + hi * 8];
    int n = nb * 128 + wn + i * 16 + lo;
    bf4[i] = *(const bf16x8*)&WeT[(size_t)n * 32 + hi * 8];
  }
  f32x4 acc[4][4] = {};
  #pragma unroll
  for (int mi = 0; mi < 4; ++mi)
    #pragma unroll
    for (int ni = 0; ni < 4; ++ni)
      acc[mi][ni] = __builtin_amdgcn_mfma_f32_16x16x32_bf16(af[mi], bf4[ni], acc[mi][ni], 0, 0, 0);
  #pragma unroll
  for (int mi = 0; mi < 4; ++mi){
    int e0 = e_base + wm + mi * 16 + hi * 4;
    #pragma unroll
    for (int r = 0; r < 4; ++r){
      int e = e0 + r;
      if (e < rs1){
        #pragma unroll
        for (int ni = 0; ni < 4; ++ni){
          int col = nb * 128 + wn + ni * 16 + lo;
          EW[(size_t)(e - rs0) * N + col] = f2bf(acc[mi][ni][r]);
        }
      }
    }
  }
}

// ---- fused logit + online-softmax + aggregation (one wave per dst node) ----
// lane owns VEC consecutive j per chunk; FO = CHUNKS*64*VEC.
template<int CHUNKS, int VEC, typename OutT>
__global__ __launch_bounds__(256) void k_fused_agg(const unsigned short* __restrict__ XL,
    const unsigned short* __restrict__ XRb, const unsigned short* __restrict__ EW,
    const int* __restrict__ csr_src, const int* __restrict__ row_start,
    const float* __restrict__ att, const float* __restrict__ bc,
    OutT* __restrict__ out, int c0){
  const int FO = CHUNKS * 64 * VEC;
  int lane = threadIdx.x & 63;
  int wave = threadIdx.x >> 6;
  int n = c0 + blockIdx.x * 4 + wave;
  int rs0 = row_start[c0];
  int rs = row_start[n], re = row_start[n + 1];
  int jj = lane * VEC;
  float xr[CHUNKS][VEC], at[CHUNKS][VEC], acc[CHUNKS][VEC];
  #pragma unroll
  for (int c = 0; c < CHUNKS; ++c){
    int base = c * 64 * VEC + jj;
    if (VEC == 8){
      uint4 q = *(const uint4*)&XRb[(size_t)n * FO + base];
      xr[c][0] = __uint_as_float(q.x << 16); xr[c][1] = __uint_as_float(q.x & 0xffff0000u);
      xr[c][2] = __uint_as_float(q.y << 16); xr[c][3] = __uint_as_float(q.y & 0xffff0000u);
      xr[c][4] = __uint_as_float(q.z << 16); xr[c][5] = __uint_as_float(q.z & 0xffff0000u);
      xr[c][6] = __uint_as_float(q.w << 16); xr[c][7] = __uint_as_float(q.w & 0xffff0000u);
    } else {
      ushort4 u = *(const ushort4*)&XRb[(size_t)n * FO + base];
      xr[c][0] = bf2f(u.x); xr[c][1] = bf2f(u.y); xr[c][2] = bf2f(u.z); xr[c][3] = bf2f(u.w);
    }
    #pragma unroll
    for (int v = 0; v < VEC; v += 4){
      float4 a4 = *(const float4*)&att[base + v];
      at[c][v] = a4.x; at[c][v+1] = a4.y; at[c][v+2] = a4.z; at[c][v+3] = a4.w;
    }
    #pragma unroll
    for (int v = 0; v < VEC; ++v) acc[c][v] = 0.f;
  }
  float m = -1e30f, den = 0.f;
  for (int i = rs; i < re; ++i){
    int s = csr_src[i];
    const unsigned short* xp = XL + (size_t)s * FO;
    const unsigned short* ep = EW + (size_t)(i - rs0) * FO;
    float xl[CHUNKS][VEC];
    float tt = 0.f;
    #pragma unroll
    for (int c = 0; c < CHUNKS; ++c){
      int base = c * 64 * VEC + jj;
      float ew[VEC];
      if (VEC == 8){
        uint4 qx = *(const uint4*)&xp[base];
        uint4 qe = *(const uint4*)&ep[base];
        xl[c][0] = __uint_as_float(qx.x << 16); xl[c][1] = __uint_as_float(qx.x & 0xffff0000u);
        xl[c][2] = __uint_as_float(qx.y << 16); xl[c][3] = __uint_as_float(qx.y & 0xffff0000u);
        xl[c][4] = __uint_as_float(qx.z << 16); xl[c][5] = __uint_as_float(qx.z & 0xffff0000u);
        xl[c][6] = __uint_as_float(qx.w << 16); xl[c][7] = __uint_as_float(qx.w & 0xffff0000u);
        ew[0] = __uint_as_float(qe.x << 16); ew[1] = __uint_as_float(qe.x & 0xffff0000u);
        ew[2] = __uint_as_float(qe.y << 16); ew[3] = __uint_as_float(qe.y & 0xffff0000u);
        ew[4] = __uint_as_float(qe.z << 16); ew[5] = __uint_as_float(qe.z & 0xffff0000u);
        ew[6] = __uint_as_float(qe.w << 16); ew[7] = __uint_as_float(qe.w & 0xffff0000u);
      } else {
        ushort4 ux = *(const ushort4*)&xp[base];
        ushort4 ue = *(const ushort4*)&ep[base];
        xl[c][0] = bf2f(ux.x); xl[c][1] = bf2f(ux.y); xl[c][2] = bf2f(ux.z); xl[c][3] = bf2f(ux.w);
        ew[0] = bf2f(ue.x); ew[1] = bf2f(ue.y); ew[2] = bf2f(ue.z); ew[3] = bf2f(ue.w);
      }
      #pragma unroll
      for (int v = 0; v < VEC; ++v)
        tt += at[c][v] * lrelu(xl[c][v] + xr[c][v] + ew[v]);
    }
    tt = wredsum(tt);
    float mn = fmaxf(m, tt);
    float scale = __expf(m - mn);   // first iter: exp(-huge) = 0
    float f = __expf(tt - mn);
    den = den * scale + f;
    #pragma unroll
    for (int c = 0; c < CHUNKS; ++c)
      #pragma unroll
      for (int v = 0; v < VEC; ++v)
        acc[c][v] = acc[c][v] * scale + f * xl[c][v];
    m = mn;
  }
  float inv = 1.f / den;
  #pragma unroll
  for (int c = 0; c < CHUNKS; ++c){
    int base = c * 64 * VEC + jj;
    #pragma unroll
    for (int v = 0; v < VEC; ++v){
      float b = bc[base + v];
      float o = fmaxf(acc[c][v] * inv + b, 0.f);
      if (sizeof(OutT) == 4) ((float*)out)[(size_t)n * FO + base + v] = o;
      else ((unsigned short*)out)[(size_t)n * FO + base + v] = f2bf(o);
    }
  }
}

// ---- fused pool + fc1 (one block per graph; batch is sorted) ----------------
__global__ void k_poolfc(const float* __restrict__ H, const int* __restrict__ batch,
                         const float* __restrict__ w, const float* __restrict__ b,
                         float* __restrict__ z, int N){
  __shared__ float ps[256];
  __shared__ int se[2];
  int g = blockIdx.x;
  int t = threadIdx.x;
  if (t < 2){
    int target = g + t;
    int lo = 0, hi = N;
    while (lo < hi){ int mid = (lo + hi) >> 1; if (batch[mid] < target) lo = mid + 1; else hi = mid; }
    se[t] = lo;
  }
  __syncthreads();
  int s = se[0], e = se[1];
  float a = 0.f;
  for (int n = s; n < e; ++n) a += H[(size_t)n * 256 + t];
  ps[t] = a;
  __syncthreads();
  if (t < 64){
    float acc = 0.f;
    for (int k = 0; k < 256; ++k) acc += ps[k] * w[k * 64 + t];
    z[g * 64 + t] = acc / fmaxf((float)(e - s), 1.f) + b[t];
  }
}

__global__ void k_head(const float* __restrict__ z, const float* __restrict__ bn_g,
                       const float* __restrict__ bn_b, const float* __restrict__ w2,
                       const float* __restrict__ b2, float* __restrict__ out){
  __shared__ float mu_s[64], is_s[64];
  int t = threadIdx.x;  // 128 threads
  if (t < 64){
    float mu = 0.f, m2 = 0.f;
    for (int g = 0; g < 128; ++g){ float v = z[g * 64 + t]; mu += v; m2 += v * v; }
    mu /= 128.f; m2 /= 128.f;
    float var = m2 - mu * mu;
    mu_s[t] = mu;
    is_s[t] = rsqrtf(var + 1e-5f);
  }
  __syncthreads();
  float o = b2[0];
  for (int j = 0; j < 64; ++j){
    float v = (z[t * 64 + j] - mu_s[j]) * is_s[j] * bn_g[j] + bn_b[j];
    o += fmaxf(v, 0.f) * w2[j];
  }
  out[t] = o;
}

extern "C" void kernel_launch(void* const* d_in, const int* in_sizes, int n_in,
                              void* d_out, int out_size, void* d_ws, size_t ws_size,
                              hipStream_t stream){
  const int N = 16384, E = 131072, Eaug = E + N, NG = 128;
  const float* x     = (const float*)d_in[0];
  const int*   ei    = (const int*)  d_in[1];
  const float* ea    = (const float*)d_in[2];
  const int*   batch = (const int*)  d_in[3];
  const float* Wl[3]  = {(const float*)d_in[4],  (const float*)d_in[11], (const float*)d_in[18]};
  const float* bl[3]  = {(const float*)d_in[5],  (const float*)d_in[12], (const float*)d_in[19]};
  const float* Wr[3]  = {(const float*)d_in[6],  (const float*)d_in[13], (const float*)d_in[20]};
  const float* br[3]  = {(const float*)d_in[7],  (const float*)d_in[14], (const float*)d_in[21]};
  const float* We[3]  = {(const float*)d_in[8],  (const float*)d_in[15], (const float*)d_in[22]};
  const float* att[3] = {(const float*)d_in[9],  (const float*)d_in[16], (const float*)d_in[23]};
  const float* bc[3]  = {(const float*)d_in[10], (const float*)d_in[17], (const float*)d_in[24]};
  const float* fc1_w = (const float*)d_in[25];
  const float* fc1_b = (const float*)d_in[26];
  const float* bn_g  = (const float*)d_in[27];
  const float* bn_b  = (const float*)d_in[28];
  const float* fc2_w = (const float*)d_in[29];
  const float* fc2_b = (const float*)d_in[30];
  float* out = (float*)d_out;

  char* wsb = (char*)d_ws;
  size_t off = 0;
  auto alloc = [&](size_t bytes) -> char* {
    char* p = wsb + off;
    off = (off + bytes + 255) & ~(size_t)255;
    return p;
  };
  int*   deg       = (int*)  alloc((size_t)N * 4);
  int*   fill      = (int*)  alloc((size_t)N * 4);
  int*   row_start = (int*)  alloc((size_t)(N + 1) * 4);
  int*   csr_src   = (int*)  alloc((size_t)Eaug * 4);
  int*   csr_eid   = (int*)  alloc((size_t)Eaug * 4);
  unsigned short* ea_perm = (unsigned short*)alloc((size_t)Eaug * 32 * 2);
  unsigned short* XL   = (unsigned short*)alloc((size_t)N * 1024 * 2); // 32 MB
  unsigned short* XRb  = (unsigned short*)alloc((size_t)N * 1024 * 2); // 32 MB
  unsigned short* bufA = (unsigned short*)alloc((size_t)N * 1024 * 2); // 32 MB: Xb / L2-out
  unsigned short* bufB = (unsigned short*)alloc((size_t)N * 512 * 4);  // 32 MB: L1-out bf16 / L3-out fp32
  unsigned short* WtL  = (unsigned short*)alloc((size_t)1024 * 1024 * 2);
  unsigned short* WtR  = (unsigned short*)alloc((size_t)1024 * 1024 * 2);
  unsigned short* WeT  = (unsigned short*)alloc((size_t)1024 * 32 * 2);
  float* zbuf      = (float*)alloc((size_t)NG * 64 * 4);
  // EW ring gets ALL remaining workspace (~125 MB at ws_size ~268 MB)
  size_t ewbytes = (ws_size > off) ? (ws_size - off) : 0;
  if (ewbytes > ((size_t)512 << 20)) ewbytes = (size_t)512 << 20;
  unsigned short* EWbuf = (unsigned short*)(wsb + off);

  hipMemsetAsync(deg, 0, (size_t)2 * N * 4, stream);  // deg + fill (adjacent)

  k_deg<<<E / 256, 256, 0, stream>>>(ei, deg, E);
  k_scan<<<1, 256, 0, stream>>>(deg, row_start, N);
  k_csr_build<<<(N + E) / 256, 256, 0, stream>>>(ei, row_start, fill, csr_src, csr_eid, N, E);
  k_eaprep<<<(N * 32 + Eaug * 8 + 255) / 256, 256, 0, stream>>>(ea, csr_eid, row_start, ea_perm, N, Eaug, E);
  k_cvt_bf16<<<(N * 256 / 4) / 256, 256, 0, stream>>>(x, bufA, N * 256 / 4);  // Xb in bufA

  const int fin[3] = {256, 512, 1024};
  const int fo[3]  = {512, 1024, 256};
  const unsigned short* Ain[3] = {bufA, bufB, bufA};

  for (int L = 0; L < 3; ++L){
    int FI = fin[L], FO = fo[L];
    k_transpose2_bf16<<<dim3(FO / 64, FI / 64, 2), 256, 0, stream>>>(Wl[L], Wr[L], WtL, WtR, FI, FO);
    k_transpose_we<<<(32 * FO + 255) / 256, 256, 0, stream>>>(We[L], WeT, FO);
    // M-tile = blockIdx.x (128 blocks, %8==0): XCD-locality for A
    dim3 gg(N / 128, FO / 128, 2);
    k_mfma_gemm2<<<gg, 256, 0, stream>>>(Ain[L], WtL, WtR, bl[L], br[L], XL, XRb, FO, FI);

    // chunk sizing from actual EW capacity: mean edges = 9*npc, keep 10*npc+5120 <= budget
    size_t budget = ewbytes / ((size_t)FO * 2);
    int npc = 4;
    while (npc < N){
      long next = (long)npc * 2;
      if (10L * next + 5120 <= (long)budget) npc = (int)next; else break;
    }
    int nchunks = N / npc;
    int ewrows = (int)((10L * npc + 4096 + 127) / 128);
    ewrows = (ewrows + 7) & ~7;   // multiple of 8 for XCD swizzle
    for (int c = 0; c < nchunks; ++c){
      dim3 eg(ewrows, FO / 128);  // edge-tile = blockIdx.x
      k_mfma_ew<<<eg, 256, 0, stream>>>(ea_perm, WeT, EWbuf, row_start, c * npc, (c + 1) * npc, FO);
      if (FO == 512)
        k_fused_agg<1, 8, unsigned short><<<npc / 4, 256, 0, stream>>>(XL, XRb, EWbuf, csr_src, row_start, att[L], bc[L], bufB, c * npc);
      else if (FO == 1024)
        k_fused_agg<2, 8, unsigned short><<<npc / 4, 256, 0, stream>>>(XL, XRb, EWbuf, csr_src, row_start, att[L], bc[L], bufA, c * npc);
      else
        k_fused_agg<1, 4, float><<<npc / 4, 256, 0, stream>>>(XL, XRb, EWbuf, csr_src, row_start, att[L], bc[L], (float*)bufB, c * npc);
    }
  }

  k_poolfc<<<NG, 256, 0, stream>>>((const float*)bufB, batch, fc1_w, fc1_b, zbuf, N);
  k_head<<<1, 128, 0, stream>>>(zbuf, bn_g, bn_b, fc2_w, fc2_b, out);
}

// Round 13
// 648.000 us; speedup vs baseline: 1.2903x; 1.0347x over previous
//
#include <hip/hip_runtime.h>
#include <hip/hip_bf16.h>
#include <math.h>

#define NEG_SLOPE 0.2f

typedef short bf16x8 __attribute__((ext_vector_type(8)));
typedef float f32x4 __attribute__((ext_vector_type(4)));

__device__ __forceinline__ float wredsum(float v){
  #pragma unroll
  for (int o = 32; o; o >>= 1) v += __shfl_xor(v, o, 64);
  return v;
}
__device__ __forceinline__ float lrelu(float x){ return x >= 0.f ? x : NEG_SLOPE * x; }
__device__ __forceinline__ unsigned short f2bf(float f){
  __hip_bfloat16 h = __float2bfloat16(f);
  return *(unsigned short*)&h;
}
__device__ __forceinline__ float bf2f(unsigned short u){
  return __uint_as_float((unsigned)u << 16);
}

// async global->LDS, 16B per lane; lds dst = wave-uniform base + lane*16
__device__ __forceinline__ void gload_lds16(const unsigned short* g, unsigned short* l){
  __builtin_amdgcn_global_load_lds(
      (const __attribute__((address_space(1))) unsigned int*)g,
      (__attribute__((address_space(3))) unsigned int*)l, 16, 0, 0);
}

// ---- CSR construction ------------------------------------------------------
__global__ void k_deg(const int* __restrict__ ei, int* __restrict__ deg, int E){
  int e = blockIdx.x * 256 + threadIdx.x;
  if (e >= E) return;
  atomicAdd(&deg[ei[E + e]], 1);
}

// row width = deg[n] + 1 (self loop).  N = 16384 = 256 * 64, single block scan.
__global__ void k_scan(const int* __restrict__ deg, int* __restrict__ row_start, int N){
  __shared__ int s[256];
  int t = threadIdx.x;
  int base = t * 64;
  int sum = 0;
  for (int i = 0; i < 64; ++i) sum += deg[base + i] + 1;
  s[t] = sum;
  __syncthreads();
  for (int off = 1; off < 256; off <<= 1){
    int v = (t >= off) ? s[t - off] : 0;
    __syncthreads();
    s[t] += v;
    __syncthreads();
  }
  int run = s[t] - sum;   // exclusive
  for (int i = 0; i < 64; ++i){ row_start[base + i] = run; run += deg[base + i] + 1; }
  if (t == 255) row_start[N] = run;
}

// self slots (idx < N) + edge slots (idx >= N) in one launch
__global__ void k_csr_build(const int* __restrict__ ei, const int* __restrict__ row_start,
                            int* __restrict__ fill, int* __restrict__ csr_src,
                            int* __restrict__ csr_eid, int N, int E){
  int idx = blockIdx.x * 256 + threadIdx.x;
  if (idx < N){
    int p = row_start[idx];
    csr_src[p] = idx;        // self loop in slot 0
    csr_eid[p] = E;          // sentinel
  } else {
    int e = idx - N;
    if (e >= E) return;
    int dst = ei[E + e];
    int p = row_start[dst] + 1 + atomicAdd(&fill[dst], 1);
    csr_src[p] = ei[e];
    csr_eid[p] = e;
  }
}

// merged: self-loop mean attr (first N*32 threads) + permuted bf16 copy (rest)
__global__ void k_eaprep(const float* __restrict__ ea, const int* __restrict__ csr_eid,
                         const int* __restrict__ row_start,
                         unsigned short* __restrict__ ea_perm, int N, int Eaug, int E){
  int idx = blockIdx.x * 256 + threadIdx.x;
  if (idx < N * 32){
    int n = idx >> 5, k = idx & 31;
    int rs = row_start[n], re = row_start[n + 1];
    float sum = 0.f;
    for (int i = rs + 1; i < re; ++i)
      sum += ea[(size_t)csr_eid[i] * 32 + k];
    float d = (float)max(re - rs - 1, 1);
    ea_perm[(size_t)rs * 32 + k] = f2bf(sum / d);
  } else {
    int j = idx - N * 32;
    int p = j >> 3, q = j & 7;
    if (p >= Eaug) return;
    int e = csr_eid[p];
    if (e >= E) return;   // self slot handled above
    float4 v = ((const float4*)(ea + (size_t)e * 32))[q];
    ushort4 o;
    o.x = f2bf(v.x); o.y = f2bf(v.y); o.z = f2bf(v.z); o.w = f2bf(v.w);
    *(ushort4*)&ea_perm[(size_t)p * 32 + q * 4] = o;
  }
}

// ---- dtype prep ------------------------------------------------------------
__global__ void k_cvt_bf16(const float* __restrict__ in, unsigned short* __restrict__ out, int n4){
  int idx = blockIdx.x * 256 + threadIdx.x;
  if (idx >= n4) return;
  float4 v = *(const float4*)&in[idx * 4];
  ushort4 o;
  o.x = f2bf(v.x); o.y = f2bf(v.y); o.z = f2bf(v.z); o.w = f2bf(v.w);
  *(ushort4*)&out[idx * 4] = o;
}

// ---- weight prep ------------------------------------------------------------
// W[K,N] fp32 -> Wt[N,K] bf16; blockIdx.z selects (W0->Wt0, W1->Wt1).
__global__ __launch_bounds__(256) void k_transpose2_bf16(const float* __restrict__ W0,
    const float* __restrict__ W1, unsigned short* __restrict__ Wt0,
    unsigned short* __restrict__ Wt1, int K, int N){
  __shared__ float tile[64][65];
  const float* W = blockIdx.z ? W1 : W0;
  unsigned short* Wt = blockIdx.z ? Wt1 : Wt0;
  int n0 = blockIdx.x * 64, k0 = blockIdx.y * 64;
  int col = threadIdx.x & 63, rq = threadIdx.x >> 6;
  #pragma unroll
  for (int i = 0; i < 16; ++i){
    int r = rq * 16 + i;
    tile[r][col] = W[(size_t)(k0 + r) * N + n0 + col];
  }
  __syncthreads();
  #pragma unroll
  for (int i = 0; i < 16; ++i){
    int r = rq * 16 + i;
    Wt[(size_t)(n0 + r) * K + k0 + col] = f2bf(tile[col][r]);
  }
}

__global__ void k_transpose_we(const float* __restrict__ We, unsigned short* __restrict__ WeT, int FO){
  int idx = blockIdx.x * 256 + threadIdx.x;
  if (idx >= 32 * FO) return;
  int k = idx / FO, n = idx % FO;
  WeT[n * 32 + k] = f2bf(We[idx]);
}

// ---- bf16 MFMA GEMM, dual-output (z: 0->L, 1->R), BK=64 split-half ---------
// (r12 structure: XCD M-tile swizzle, global_load_lds staging, BK=64,
// LDS-repacked coalesced epilogue)
__global__ void k_mfma_gemm2(const unsigned short* __restrict__ A,
    const unsigned short* __restrict__ BtL, const unsigned short* __restrict__ BtR,
    const float* __restrict__ biasL, const float* __restrict__ biasR,
    unsigned short* __restrict__ CL, unsigned short* __restrict__ CR, int FO, int K){
  __shared__ unsigned short lds[16384];     // 32 KB: As0|As1|Bs0|Bs1 / C-tile
  unsigned short* As0 = lds;                // [128][32], K-half 0
  unsigned short* As1 = lds + 4096;         // [128][32], K-half 1
  unsigned short* Bs0 = lds + 8192;
  unsigned short* Bs1 = lds + 12288;
  const unsigned short* Bt = blockIdx.z ? BtR : BtL;
  const float* bias = blockIdx.z ? biasR : biasL;
  unsigned short* C = blockIdx.z ? CR : CL;
  int t = threadIdx.x;
  int mb = blockIdx.x, nb = blockIdx.y;
  int lane = t & 63, w = t >> 6;
  int wm = (w & 1) * 64, wn = (w >> 1) * 64;
  int lo = lane & 15, hi = lane >> 4;
  int srow = w * 32 + (lane >> 2);
  int scol = (lane & 3) * 8;                 // shorts
  const unsigned short* Ap0 = A + (size_t)(mb * 128 + srow) * K + scol;
  const unsigned short* Ap1 = Ap0 + (size_t)16 * K;
  const unsigned short* Bp0 = Bt + (size_t)(nb * 128 + srow) * K + scol;
  const unsigned short* Bp1 = Bp0 + (size_t)16 * K;
  unsigned short* Ad00 = As0 + (w * 32) * 32;       // wave-uniform LDS bases
  unsigned short* Ad01 = As0 + (w * 32 + 16) * 32;
  unsigned short* Ad10 = As1 + (w * 32) * 32;
  unsigned short* Ad11 = As1 + (w * 32 + 16) * 32;
  unsigned short* Bd00 = Bs0 + (w * 32) * 32;
  unsigned short* Bd01 = Bs0 + (w * 32 + 16) * 32;
  unsigned short* Bd10 = Bs1 + (w * 32) * 32;
  unsigned short* Bd11 = Bs1 + (w * 32 + 16) * 32;
  f32x4 acc[4][4] = {};
  for (int k0 = 0; k0 < K; k0 += 64){
    gload_lds16(Ap0 + k0, Ad00);
    gload_lds16(Ap1 + k0, Ad01);
    gload_lds16(Ap0 + k0 + 32, Ad10);
    gload_lds16(Ap1 + k0 + 32, Ad11);
    gload_lds16(Bp0 + k0, Bd00);
    gload_lds16(Bp1 + k0, Bd01);
    gload_lds16(Bp0 + k0 + 32, Bd10);
    gload_lds16(Bp1 + k0 + 32, Bd11);
    __syncthreads();
    #pragma unroll
    for (int ks = 0; ks < 2; ++ks){
      const unsigned short* Asx = ks ? As1 : As0;
      const unsigned short* Bsx = ks ? Bs1 : Bs0;
      bf16x8 af[4], bfr[4];
      #pragma unroll
      for (int i = 0; i < 4; ++i){
        af[i]  = *(const bf16x8*)&Asx[(wm + i * 16 + lo) * 32 + hi * 8];
        bfr[i] = *(const bf16x8*)&Bsx[(wn + i * 16 + lo) * 32 + hi * 8];
      }
      #pragma unroll
      for (int mi = 0; mi < 4; ++mi)
        #pragma unroll
        for (int ni = 0; ni < 4; ++ni)
          acc[mi][ni] = __builtin_amdgcn_mfma_f32_16x16x32_bf16(af[mi], bfr[ni], acc[mi][ni], 0, 0, 0);
    }
    __syncthreads();
  }
  // epilogue: acc -> LDS C-tile [128][128] shorts -> coalesced dwordx4 stores
  #pragma unroll
  for (int ni = 0; ni < 4; ++ni){
    int col = wn + ni * 16 + lo;
    float bv = bias[nb * 128 + col];
    #pragma unroll
    for (int mi = 0; mi < 4; ++mi){
      int row = wm + mi * 16 + hi * 4;
      #pragma unroll
      for (int r = 0; r < 4; ++r)
        lds[(row + r) * 128 + col] = f2bf(acc[mi][ni][r] + bv);
    }
  }
  __syncthreads();
  #pragma unroll
  for (int q = 0; q < 8; ++q){
    int idx = q * 256 + t;
    int row = idx >> 4;
    int cs = (idx & 15) * 8;
    *(float4*)&C[(size_t)(mb * 128 + row) * FO + nb * 128 + cs] = *(float4*)&lds[row * 128 + cs];
  }
}

// ---- EW MFMA GEMM (K=32, no LDS): EW[e-rs0,:] = ea_perm[e,:] @ WeT[n,:]^T --
// blockIdx.x = edge-tile (grid %8): XCD locality for ea rows.
__global__ void k_mfma_ew(const unsigned short* __restrict__ Ap,
    const unsigned short* __restrict__ WeT, unsigned short* __restrict__ EW,
    const int* __restrict__ row_start, int c0, int c1, int N){
  int rs0 = row_start[c0], rs1 = row_start[c1];
  int e_base = rs0 + blockIdx.x * 128;
  if (e_base >= rs1) return;
  int t = threadIdx.x;
  int nb = blockIdx.y;
  int lane = t & 63, w = t >> 6;
  int wm = (w & 1) * 64, wn = (w >> 1) * 64;
  int lo = lane & 15, hi = lane >> 4;
  bf16x8 af[4], bf4[4];
  #pragma unroll
  for (int i = 0; i < 4; ++i){
    int e = min(e_base + wm + i * 16 + lo, rs1 - 1);
    af[i] = *(const bf16x8*)&Ap[(size_t)e * 32 + hi * 8];
    int n = nb * 128 + wn + i * 16 + lo;
    bf4[i] = *(const bf16x8*)&WeT[(size_t)n * 32 + hi * 8];
  }
  f32x4 acc[4][4] = {};
  #pragma unroll
  for (int mi = 0; mi < 4; ++mi)
    #pragma unroll
    for (int ni = 0; ni < 4; ++ni)
      acc[mi][ni] = __builtin_amdgcn_mfma_f32_16x16x32_bf16(af[mi], bf4[ni], acc[mi][ni], 0, 0, 0);
  #pragma unroll
  for (int mi = 0; mi < 4; ++mi){
    int e0 = e_base + wm + mi * 16 + hi * 4;
    #pragma unroll
    for (int r = 0; r < 4; ++r){
      int e = e0 + r;
      if (e < rs1){
        #pragma unroll
        for (int ni = 0; ni < 4; ++ni){
          int col = nb * 128 + wn + ni * 16 + lo;
          EW[(size_t)(e - rs0) * N + col] = f2bf(acc[mi][ni][r]);
        }
      }
    }
  }
}

// ---- fused logit + online-softmax + aggregation (one wave per dst node) ----
// lane owns VEC consecutive j per chunk; FO = CHUNKS*64*VEC.
template<int CHUNKS, int VEC, typename OutT>
__global__ __launch_bounds__(256) void k_fused_agg(const unsigned short* __restrict__ XL,
    const unsigned short* __restrict__ XRb, const unsigned short* __restrict__ EW,
    const int* __restrict__ csr_src, const int* __restrict__ row_start,
    const float* __restrict__ att, const float* __restrict__ bc,
    OutT* __restrict__ out, int c0){
  const int FO = CHUNKS * 64 * VEC;
  int lane = threadIdx.x & 63;
  int wave = threadIdx.x >> 6;
  int n = c0 + blockIdx.x * 4 + wave;
  int rs0 = row_start[c0];
  int rs = row_start[n], re = row_start[n + 1];
  int jj = lane * VEC;
  float xr[CHUNKS][VEC], at[CHUNKS][VEC], acc[CHUNKS][VEC];
  #pragma unroll
  for (int c = 0; c < CHUNKS; ++c){
    int base = c * 64 * VEC + jj;
    if (VEC == 8){
      uint4 q = *(const uint4*)&XRb[(size_t)n * FO + base];
      xr[c][0] = __uint_as_float(q.x << 16); xr[c][1] = __uint_as_float(q.x & 0xffff0000u);
      xr[c][2] = __uint_as_float(q.y << 16); xr[c][3] = __uint_as_float(q.y & 0xffff0000u);
      xr[c][4] = __uint_as_float(q.z << 16); xr[c][5] = __uint_as_float(q.z & 0xffff0000u);
      xr[c][6] = __uint_as_float(q.w << 16); xr[c][7] = __uint_as_float(q.w & 0xffff0000u);
    } else {
      ushort4 u = *(const ushort4*)&XRb[(size_t)n * FO + base];
      xr[c][0] = bf2f(u.x); xr[c][1] = bf2f(u.y); xr[c][2] = bf2f(u.z); xr[c][3] = bf2f(u.w);
    }
    #pragma unroll
    for (int v = 0; v < VEC; v += 4){
      float4 a4 = *(const float4*)&att[base + v];
      at[c][v] = a4.x; at[c][v+1] = a4.y; at[c][v+2] = a4.z; at[c][v+3] = a4.w;
    }
    #pragma unroll
    for (int v = 0; v < VEC; ++v) acc[c][v] = 0.f;
  }
  float m = -1e30f, den = 0.f;
  for (int i = rs; i < re; ++i){
    int s = csr_src[i];
    const unsigned short* xp = XL + (size_t)s * FO;
    const unsigned short* ep = EW + (size_t)(i - rs0) * FO;
    float xl[CHUNKS][VEC];
    float tt = 0.f;
    #pragma unroll
    for (int c = 0; c < CHUNKS; ++c){
      int base = c * 64 * VEC + jj;
      float ew[VEC];
      if (VEC == 8){
        uint4 qx = *(const uint4*)&xp[base];
        uint4 qe = *(const uint4*)&ep[base];
        xl[c][0] = __uint_as_float(qx.x << 16); xl[c][1] = __uint_as_float(qx.x & 0xffff0000u);
        xl[c][2] = __uint_as_float(qx.y << 16); xl[c][3] = __uint_as_float(qx.y & 0xffff0000u);
        xl[c][4] = __uint_as_float(qx.z << 16); xl[c][5] = __uint_as_float(qx.z & 0xffff0000u);
        xl[c][6] = __uint_as_float(qx.w << 16); xl[c][7] = __uint_as_float(qx.w & 0xffff0000u);
        ew[0] = __uint_as_float(qe.x << 16); ew[1] = __uint_as_float(qe.x & 0xffff0000u);
        ew[2] = __uint_as_float(qe.y << 16); ew[3] = __uint_as_float(qe.y & 0xffff0000u);
        ew[4] = __uint_as_float(qe.z << 16); ew[5] = __uint_as_float(qe.z & 0xffff0000u);
        ew[6] = __uint_as_float(qe.w << 16); ew[7] = __uint_as_float(qe.w & 0xffff0000u);
      } else {
        ushort4 ux = *(const ushort4*)&xp[base];
        ushort4 ue = *(const ushort4*)&ep[base];
        xl[c][0] = bf2f(ux.x); xl[c][1] = bf2f(ux.y); xl[c][2] = bf2f(ux.z); xl[c][3] = bf2f(ux.w);
        ew[0] = bf2f(ue.x); ew[1] = bf2f(ue.y); ew[2] = bf2f(ue.z); ew[3] = bf2f(ue.w);
      }
      #pragma unroll
      for (int v = 0; v < VEC; ++v)
        tt += at[c][v] * lrelu(xl[c][v] + xr[c][v] + ew[v]);
    }
    tt = wredsum(tt);
    float mn = fmaxf(m, tt);
    float scale = __expf(m - mn);   // first iter: exp(-huge) = 0
    float f = __expf(tt - mn);
    den = den * scale + f;
    #pragma unroll
    for (int c = 0; c < CHUNKS; ++c)
      #pragma unroll
      for (int v = 0; v < VEC; ++v)
        acc[c][v] = acc[c][v] * scale + f * xl[c][v];
    m = mn;
  }
  float inv = 1.f / den;
  #pragma unroll
  for (int c = 0; c < CHUNKS; ++c){
    int base = c * 64 * VEC + jj;
    #pragma unroll
    for (int v = 0; v < VEC; ++v){
      float b = bc[base + v];
      float o = fmaxf(acc[c][v] * inv + b, 0.f);
      if (sizeof(OutT) == 4) ((float*)out)[(size_t)n * FO + base + v] = o;
      else ((unsigned short*)out)[(size_t)n * FO + base + v] = f2bf(o);
    }
  }
}

// ---- pooling stage A: partial sums (graph g, part p of 8) ------------------
__global__ void k_pool_part(const float* __restrict__ H, const int* __restrict__ batch,
                            float* __restrict__ partial, int N){
  __shared__ int se[2];
  int g = blockIdx.x, part = blockIdx.y;
  int t = threadIdx.x;
  if (t < 2){
    int target = g + t;
    int lo = 0, hi = N;
    while (lo < hi){ int mid = (lo + hi) >> 1; if (batch[mid] < target) lo = mid + 1; else hi = mid; }
    se[t] = lo;
  }
  __syncthreads();
  int s = se[0], e = se[1];
  int len = e - s;
  int p0 = s + (int)((long)len * part / 8);
  int p1 = s + (int)((long)len * (part + 1) / 8);
  float a = 0.f;
  for (int n = p0; n < p1; ++n) a += H[(size_t)n * 256 + t];
  partial[((size_t)g * 8 + part) * 256 + t] = a;
}

// ---- pooling stage B: combine partials + fc1 -------------------------------
__global__ void k_fc1b(const float* __restrict__ partial, const int* __restrict__ batch,
                       const float* __restrict__ w, const float* __restrict__ b,
                       float* __restrict__ z, int N){
  __shared__ float ps[256];
  __shared__ int se[2];
  int g = blockIdx.x;
  int t = threadIdx.x;
  if (t < 2){
    int target = g + t;
    int lo = 0, hi = N;
    while (lo < hi){ int mid = (lo + hi) >> 1; if (batch[mid] < target) lo = mid + 1; else hi = mid; }
    se[t] = lo;
  }
  float a = 0.f;
  #pragma unroll
  for (int p = 0; p < 8; ++p) a += partial[((size_t)g * 8 + p) * 256 + t];
  ps[t] = a;
  __syncthreads();
  if (t < 64){
    float acc = 0.f;
    for (int k = 0; k < 256; ++k) acc += ps[k] * w[k * 64 + t];
    z[g * 64 + t] = acc / fmaxf((float)(se[1] - se[0]), 1.f) + b[t];
  }
}

__global__ void k_head(const float* __restrict__ z, const float* __restrict__ bn_g,
                       const float* __restrict__ bn_b, const float* __restrict__ w2,
                       const float* __restrict__ b2, float* __restrict__ out){
  __shared__ float mu_s[64], is_s[64];
  int t = threadIdx.x;  // 128 threads
  if (t < 64){
    float mu = 0.f, m2 = 0.f;
    for (int g = 0; g < 128; ++g){ float v = z[g * 64 + t]; mu += v; m2 += v * v; }
    mu /= 128.f; m2 /= 128.f;
    float var = m2 - mu * mu;
    mu_s[t] = mu;
    is_s[t] = rsqrtf(var + 1e-5f);
  }
  __syncthreads();
  float o = b2[0];
  for (int j = 0; j < 64; ++j){
    float v = (z[t * 64 + j] - mu_s[j]) * is_s[j] * bn_g[j] + bn_b[j];
    o += fmaxf(v, 0.f) * w2[j];
  }
  out[t] = o;
}

extern "C" void kernel_launch(void* const* d_in, const int* in_sizes, int n_in,
                              void* d_out, int out_size, void* d_ws, size_t ws_size,
                              hipStream_t stream){
  const int N = 16384, E = 131072, Eaug = E + N, NG = 128;
  const float* x     = (const float*)d_in[0];
  const int*   ei    = (const int*)  d_in[1];
  const float* ea    = (const float*)d_in[2];
  const int*   batch = (const int*)  d_in[3];
  const float* Wl[3]  = {(const float*)d_in[4],  (const float*)d_in[11], (const float*)d_in[18]};
  const float* bl[3]  = {(const float*)d_in[5],  (const float*)d_in[12], (const float*)d_in[19]};
  const float* Wr[3]  = {(const float*)d_in[6],  (const float*)d_in[13], (const float*)d_in[20]};
  const float* br[3]  = {(const float*)d_in[7],  (const float*)d_in[14], (const float*)d_in[21]};
  const float* We[3]  = {(const float*)d_in[8],  (const float*)d_in[15], (const float*)d_in[22]};
  const float* att[3] = {(const float*)d_in[9],  (const float*)d_in[16], (const float*)d_in[23]};
  const float* bc[3]  = {(const float*)d_in[10], (const float*)d_in[17], (const float*)d_in[24]};
  const float* fc1_w = (const float*)d_in[25];
  const float* fc1_b = (const float*)d_in[26];
  const float* bn_g  = (const float*)d_in[27];
  const float* bn_b  = (const float*)d_in[28];
  const float* fc2_w = (const float*)d_in[29];
  const float* fc2_b = (const float*)d_in[30];
  float* out = (float*)d_out;

  char* wsb = (char*)d_ws;
  size_t off = 0;
  auto alloc = [&](size_t bytes) -> char* {
    char* p = wsb + off;
    off = (off + bytes + 255) & ~(size_t)255;
    return p;
  };
  int*   deg       = (int*)  alloc((size_t)N * 4);
  int*   fill      = (int*)  alloc((size_t)N * 4);
  int*   row_start = (int*)  alloc((size_t)(N + 1) * 4);
  int*   csr_src   = (int*)  alloc((size_t)Eaug * 4);
  int*   csr_eid   = (int*)  alloc((size_t)Eaug * 4);
  unsigned short* ea_perm = (unsigned short*)alloc((size_t)Eaug * 32 * 2);
  unsigned short* XL   = (unsigned short*)alloc((size_t)N * 1024 * 2); // 32 MB
  unsigned short* XRb  = (unsigned short*)alloc((size_t)N * 1024 * 2); // 32 MB
  unsigned short* bufA = (unsigned short*)alloc((size_t)N * 1024 * 2); // 32 MB: Xb / L2-out
  unsigned short* bufB = (unsigned short*)alloc((size_t)N * 512 * 4);  // 32 MB: L1-out bf16 / L3-out fp32
  unsigned short* WtL  = (unsigned short*)alloc((size_t)1024 * 1024 * 2);
  unsigned short* WtR  = (unsigned short*)alloc((size_t)1024 * 1024 * 2);
  unsigned short* WeT  = (unsigned short*)alloc((size_t)1024 * 32 * 2);
  float* ppart     = (float*)alloc((size_t)NG * 8 * 256 * 4);
  float* zbuf      = (float*)alloc((size_t)NG * 64 * 4);
  // EW ring gets ALL remaining workspace (~125 MB at ws_size ~268 MB)
  size_t ewbytes = (ws_size > off) ? (ws_size - off) : 0;
  if (ewbytes > ((size_t)512 << 20)) ewbytes = (size_t)512 << 20;
  unsigned short* EWbuf = (unsigned short*)(wsb + off);

  hipMemsetAsync(deg, 0, (size_t)2 * N * 4, stream);  // deg + fill (adjacent)

  k_deg<<<E / 256, 256, 0, stream>>>(ei, deg, E);
  k_scan<<<1, 256, 0, stream>>>(deg, row_start, N);
  k_csr_build<<<(N + E) / 256, 256, 0, stream>>>(ei, row_start, fill, csr_src, csr_eid, N, E);
  k_eaprep<<<(N * 32 + Eaug * 8 + 255) / 256, 256, 0, stream>>>(ea, csr_eid, row_start, ea_perm, N, Eaug, E);
  k_cvt_bf16<<<(N * 256 / 4) / 256, 256, 0, stream>>>(x, bufA, N * 256 / 4);  // Xb in bufA

  const int fin[3] = {256, 512, 1024};
  const int fo[3]  = {512, 1024, 256};
  const unsigned short* Ain[3] = {bufA, bufB, bufA};

  for (int L = 0; L < 3; ++L){
    int FI = fin[L], FO = fo[L];
    k_transpose2_bf16<<<dim3(FO / 64, FI / 64, 2), 256, 0, stream>>>(Wl[L], Wr[L], WtL, WtR, FI, FO);
    k_transpose_we<<<(32 * FO + 255) / 256, 256, 0, stream>>>(We[L], WeT, FO);
    // M-tile = blockIdx.x (128 blocks, %8==0): XCD-locality for A
    dim3 gg(N / 128, FO / 128, 2);
    k_mfma_gemm2<<<gg, 256, 0, stream>>>(Ain[L], WtL, WtR, bl[L], br[L], XL, XRb, FO, FI);

    // chunk sizing from actual EW capacity: mean edges = 9*npc, keep 10*npc+5120 <= budget
    size_t budget = ewbytes / ((size_t)FO * 2);
    int npc = 4;
    while (npc < N){
      long next = (long)npc * 2;
      if (10L * next + 5120 <= (long)budget) npc = (int)next; else break;
    }
    int nchunks = N / npc;
    int ewrows = (int)((10L * npc + 4096 + 127) / 128);
    ewrows = (ewrows + 7) & ~7;   // multiple of 8 for XCD swizzle
    for (int c = 0; c < nchunks; ++c){
      dim3 eg(ewrows, FO / 128);  // edge-tile = blockIdx.x
      k_mfma_ew<<<eg, 256, 0, stream>>>(ea_perm, WeT, EWbuf, row_start, c * npc, (c + 1) * npc, FO);
      if (FO == 512)
        k_fused_agg<1, 8, unsigned short><<<npc / 4, 256, 0, stream>>>(XL, XRb, EWbuf, csr_src, row_start, att[L], bc[L], bufB, c * npc);
      else if (FO == 1024)
        k_fused_agg<2, 8, unsigned short><<<npc / 4, 256, 0, stream>>>(XL, XRb, EWbuf, csr_src, row_start, att[L], bc[L], bufA, c * npc);
      else
        k_fused_agg<1, 4, float><<<npc / 4, 256, 0, stream>>>(XL, XRb, EWbuf, csr_src, row_start, att[L], bc[L], (float*)bufB, c * npc);
    }
  }

  k_pool_part<<<dim3(NG, 8), 256, 0, stream>>>((const float*)bufB, batch, ppart, N);
  k_fc1b<<<NG, 256, 0, stream>>>(ppart, batch, fc1_w, fc1_b, zbuf, N);
  k_head<<<1, 128, 0, stream>>>(zbuf, bn_g, bn_b, fc2_w, fc2_b, out);
}